// Round 6
// baseline (178.737 us; speedup 1.0000x reference)
//
#include <hip/hip_runtime.h>

// corr via MFMA band extraction, 2-row wave-specialized iterations:
// out[b,(di)*9+(dj+4),h,w] = sum_c x[b,c,h,w] * y[b,c,refl(h+di-4),refl(w+dj)]
// wave wid: wp=wid>>1 -> output row (2it+wp), wt=wid&1 -> w' 16-tile.
// Deferred stores: iter it's results stored at top of it+1 (drain overlapped).

#define HH   256
#define WW   256
#define CCH  64
#define KRAD 4
#define ND   81

#define WT   16
#define HT   16
#define NIT  (HT/2)            // 8 iterations of 2 rows
#define WY   24                // staged y width = WT + 2*KRAD
#define RSTRIDE 128            // 64c * 2B, XOR-swizzled 16B chunks
#define YRING 12               // rows 2it..2it+11 window
#define YSLOT (WY * RSTRIDE)   // 3072 B

typedef __attribute__((ext_vector_type(8))) short bf16x8;
typedef __attribute__((ext_vector_type(4))) float f32x4;

__device__ __forceinline__ int reflect(int v, int n) {
    v = v < 0 ? -v : v;
    return v >= n ? 2 * n - 2 - v : v;
}
__device__ __forceinline__ unsigned f2bf_pk(float a, float b) {
    union { float f; unsigned u; } xa, xb;
    xa.f = a; xb.f = b;
    unsigned ra = (xa.u + 0x7fffu + ((xa.u >> 16) & 1u)) >> 16;
    unsigned rb = (xb.u + 0x7fffu + ((xb.u >> 16) & 1u)) >> 16;
    return ra | (rb << 16);
}
__device__ __forceinline__ int mod12(int s) {   // s in [0, 36)
    if (s >= 24) s -= 24; else if (s >= 12) s -= 12;
    return s;
}

__global__ __launch_bounds__(256, 4) void corr_mfma_kernel(
    const float* __restrict__ x, const float* __restrict__ y,
    float* __restrict__ out)
{
    __shared__ char ylds[YRING * YSLOT + 1024];   // 37888 B -> 4 blocks/CU

    // XCD-chunked bijective swizzle: 1024 blocks = 8 XCDs * 128
    const int d  = blockIdx.x;
    const int v  = (d & 7) * 128 + (d >> 3);
    const int b  = v >> 8;
    const int by = (v >> 4) & 15;
    const int bx = v & 15;
    const int w0 = bx * WT;
    const int h0 = by * HT;

    const int t    = threadIdx.x;
    const int wid  = t >> 6;
    const int lane = t & 63;
    const int lq   = lane >> 4;
    const int ln   = lane & 15;
    const int wp   = wid >> 1;       // which of the 2 rows this wave owns
    const int wt   = wid & 1;        // which w' 16-tile

    const size_t plane = (size_t)HH * WW;
    const float* yb = y + (size_t)b * CCH * plane;
    const float* xb = x + (size_t)b * CCH * plane;

    // Y staging: within each wave-pair (128 threads): yp = w' pos, ycg = c/16
    const int yp  = t & 31;
    const int ycg = (t >> 5) & 3;

    auto loadY16 = [&](int L, float* v16) {     // L = local row index (global h = h0-4+L)
        int gh = reflect(h0 - KRAD + L, HH);
        int pc = yp < WY ? yp : WY - 1;
        int gw = reflect(w0 - KRAD + pc, WW);
        const float* src = yb + (size_t)(ycg * 16) * plane + (size_t)gh * WW + gw;
#pragma unroll
        for (int j = 0; j < 16; ++j) v16[j] = src[(size_t)j * plane];
    };
    auto writeY16 = [&](int L, const float* v16) {
        if (yp < WY) {
            char* base = ylds + mod12(L) * YSLOT + yp * RSTRIDE;
            unsigned swz = ((unsigned)(yp & 7)) << 4;
#pragma unroll
            for (int p = 0; p < 2; ++p) {
                union { unsigned u[4]; uint4 q; } pk;
#pragma unroll
                for (int m = 0; m < 4; ++m)
                    pk.u[m] = f2bf_pk(v16[p * 8 + 2 * m], v16[p * 8 + 2 * m + 1]);
                *(uint4*)(base + (((unsigned)((ycg * 2 + p) * 16)) ^ swz)) = pk.q;
            }
        }
    };
    auto loadX16 = [&](int hrow, float* v16) {  // B-frag layout direct: c=lq*8+j (+32), w=w0+ln
        int gh = reflect(hrow, HH);
        const float* src = xb + (size_t)(lq * 8) * plane + (size_t)gh * WW + (w0 + ln);
#pragma unroll
        for (int j = 0; j < 8; ++j) v16[j] = src[(size_t)j * plane];
        const float* s2 = src + (size_t)32 * plane;
#pragma unroll
        for (int j = 0; j < 8; ++j) v16[8 + j] = s2[(size_t)j * plane];
    };

    // iteration-independent store masks: D row m=lq*4+r -> w'=wt*16+m, dj+4 = w'-w = m-ln+16wt
    int vr[4]; bool ok[4];
#pragma unroll
    for (int r = 0; r < 4; ++r) {
        int m = lq * 4 + r;
        vr[r] = m - ln + (wt ? 16 : 0);
        ok[r] = (unsigned)vr[r] <= 8u;
    }

    float yv[16], yv2[16], xv[16];
    bf16x8 bf0, bf1;
    f32x4 dacc[9];

    // ---- prologue: each wave-pair stages 5 Y rows (L = wp*5 .. wp*5+4), 2-deep pipelined ----
    loadY16(wp * 5 + 0, yv);
    loadY16(wp * 5 + 1, yv2);
    writeY16(wp * 5 + 0, yv);
    loadY16(wp * 5 + 2, yv);
    writeY16(wp * 5 + 1, yv2);
    loadY16(wp * 5 + 3, yv2);
    writeY16(wp * 5 + 2, yv);
    loadY16(wp * 5 + 4, yv);
    writeY16(wp * 5 + 3, yv2);
    writeY16(wp * 5 + 4, yv);
    loadX16(h0 + wp, xv);
    __syncthreads();

    // ---- main loop: 8 iterations x 2 rows ----
#pragma unroll 1
    for (int it = 0; it < NIT; ++it) {
        // convert X row (loaded last iter) -> B fragments
        {
            union { unsigned u[4]; bf16x8 v; } c0, c1;
#pragma unroll
            for (int m = 0; m < 4; ++m) {
                c0.u[m] = f2bf_pk(xv[2 * m], xv[2 * m + 1]);
                c1.u[m] = f2bf_pk(xv[8 + 2 * m], xv[9 + 2 * m]);
            }
            bf0 = c0.v; bf1 = c1.v;
        }
        // issue next-iteration staging loads (land during compute)
        const bool pf = (it < NIT - 1);
        if (pf) {
            loadY16(2 * it + 10 + wp, yv);
            loadX16(h0 + 2 * it + 2 + wp, xv);
        }
        // deferred stores of previous iteration's results (drain overlaps this compute)
        if (it > 0) {
            const int hp = h0 + 2 * (it - 1) + wp;
            float* ob = out + (size_t)b * ND * plane + (size_t)hp * WW + (w0 + ln);
#pragma unroll
            for (int k = 0; k < 9; ++k)
#pragma unroll
                for (int r = 0; r < 4; ++r)
                    if (ok[r]) ob[(size_t)(k * 9 + vr[r]) * plane] = dacc[k][r];
        }
        // compute: 9 di units, A rows from Y ring
        const int Lb = 2 * it + wp;
#pragma unroll
        for (int k = 0; k < 9; ++k) {
            const int slot = mod12(Lb + k);
            const char* ab = ylds + slot * YSLOT + (wt * 16 + ln) * RSTRIDE;
            const unsigned sw = ((unsigned)(ln & 7)) << 4;
            bf16x8 af0 = *(const bf16x8*)(ab + (((unsigned)(lq * 16)) ^ sw));
            bf16x8 af1 = *(const bf16x8*)(ab + (((unsigned)(64 + lq * 16)) ^ sw));
            f32x4 a = {0.f, 0.f, 0.f, 0.f};
            a = __builtin_amdgcn_mfma_f32_16x16x32_bf16(af0, bf0, a, 0, 0, 0);
            a = __builtin_amdgcn_mfma_f32_16x16x32_bf16(af1, bf1, a, 0, 0, 0);
            dacc[k] = a;
        }
        // stage next Y row into ring (waits on this iter's loads; compute hid them)
        if (pf) writeY16(2 * it + 10 + wp, yv);
        __syncthreads();
    }

    // epilogue: store final iteration's results
    {
        const int hp = h0 + 2 * (NIT - 1) + wp;
        float* ob = out + (size_t)b * ND * plane + (size_t)hp * WW + (w0 + ln);
#pragma unroll
        for (int k = 0; k < 9; ++k)
#pragma unroll
            for (int r = 0; r < 4; ++r)
                if (ok[r]) ob[(size_t)(k * 9 + vr[r]) * plane] = dacc[k][r];
    }
}

extern "C" void kernel_launch(void* const* d_in, const int* in_sizes, int n_in,
                              void* d_out, int out_size, void* d_ws, size_t ws_size,
                              hipStream_t stream) {
    const float* x = (const float*)d_in[0];
    const float* y = (const float*)d_in[1];
    float* out = (float*)d_out;

    dim3 grid(1024);   // 16 x 16 x 4 tiles, XCD-swizzled in-kernel -> 4 blocks/CU
    dim3 block(256);
    corr_mfma_kernel<<<grid, block, 0, stream>>>(x, y, out);
}

// Round 7
// 85.904 us; speedup vs baseline: 2.0807x; 2.0807x over previous
//
#include <hip/hip_runtime.h>
#include <hip/hip_bf16.h>

// corr via MFMA band extraction:
// out[b,(di+4)*9+(dj+4),h,w] = sum_c x[b,c,h,w] * y[b,c,refl(h+di),refl(w+dj)]
// A = Y_bf16[w'-tile, c], B = X_bf16[c, w-tile]; D[w',w] diagonals = dj.
// R7 = R4 + counted-wait barrier (T4): only lgkmcnt(0) drains at the per-row
// barrier; output stores and prefetch loads stay in flight across it.

#define HH   256
#define WW   256
#define CCH  64
#define KRAD 4
#define ND   81

#define WT   16                 // output w per block
#define HT   16                 // output h per block
#define WY   24                 // staged y width = WT + 2*KRAD
#define RSTRIDE 128             // bytes per (row,w'): 64c*2B, XOR-swizzled chunks
#define YRING 10
#define YSLOT (WY * RSTRIDE)    // 3072 B

typedef __attribute__((ext_vector_type(8))) short bf16x8;
typedef __attribute__((ext_vector_type(4))) float f32x4;

__device__ __forceinline__ int reflect(int v, int n) {
    v = v < 0 ? -v : v;
    return v >= n ? 2 * n - 2 - v : v;
}
__device__ __forceinline__ unsigned f2bf_pk(float a, float b) {
    union { float f; unsigned u; } xa, xb;
    xa.f = a; xb.f = b;
    unsigned ra = (xa.u + 0x7fffu + ((xa.u >> 16) & 1u)) >> 16;
    unsigned rb = (xb.u + 0x7fffu + ((xb.u >> 16) & 1u)) >> 16;
    return ra | (rb << 16);
}
__device__ __forceinline__ int mod10(int s) {   // s in [0, 30)
    if (s >= 20) s -= 20; else if (s >= 10) s -= 10;
    return s;
}

__global__ __launch_bounds__(256, 5) void corr_mfma_kernel(
    const float* __restrict__ x, const float* __restrict__ y,
    float* __restrict__ out)
{
    __shared__ char ylds[YRING * YSLOT];   // 30720 B

    // XCD-chunked bijective swizzle: 1024 blocks = 8 XCDs * 128
    const int d  = blockIdx.x;
    const int v  = (d & 7) * 128 + (d >> 3);
    const int b  = v >> 8;
    const int by = (v >> 4) & 15;
    const int bx = v & 15;
    const int w0 = bx * WT;
    const int h0 = by * HT;

    const int t    = threadIdx.x;
    const int wid  = t >> 6;
    const int lane = t & 63;
    const int lq   = lane >> 4;      // 0..3
    const int ln   = lane & 15;      // 0..15

    const size_t plane = (size_t)HH * WW;
    const float* yb = y + (size_t)b * CCH * plane;
    const float* xb = x + (size_t)b * CCH * plane;

    // staging lane mapping for Y rows
    const int yp  = t & 31;          // w' position, active < WY
    const int ycg = t >> 5;          // c group: c = 8*ycg + j

    auto loadY = [&](int hrow, float* v8) {
        int gh = reflect(hrow, HH);
        int pc = yp < WY ? yp : WY - 1;
        int gw = reflect(w0 - KRAD + pc, WW);
        const float* src = yb + (size_t)(ycg * 8) * plane + (size_t)gh * WW + gw;
#pragma unroll
        for (int j = 0; j < 8; ++j) v8[j] = src[(size_t)j * plane];
    };
    auto writeY = [&](int slot, const float* v8) {
        if (yp < WY) {
            // XOR chunk-swizzle: 16B chunk index ^= (row & 7)
            char* dst = ylds + slot * YSLOT + yp * RSTRIDE
                      + (((unsigned)(ycg * 16)) ^ ((unsigned)(yp & 7) << 4));
            union { unsigned u[4]; uint4 q; } pk;
#pragma unroll
            for (int m = 0; m < 4; ++m)
                pk.u[m] = f2bf_pk(v8[2 * m], v8[2 * m + 1]);
            *(uint4*)dst = pk.q;
        }
    };
    // X direct-to-register: lane (lq,ln) holds B[c = lq*8+j (+32), w0+ln]
    auto loadX = [&](int hrow, float* v16) {
        int gh = reflect(hrow, HH);
        const float* src = xb + (size_t)(lq * 8) * plane + (size_t)gh * WW + (w0 + ln);
#pragma unroll
        for (int j = 0; j < 8; ++j) v16[j] = src[(size_t)j * plane];
        const float* src2 = src + (size_t)32 * plane;
#pragma unroll
        for (int j = 0; j < 8; ++j) v16[8 + j] = src2[(size_t)j * plane];
    };
    auto xconv = [&](const float* v16, bf16x8& f0, bf16x8& f1) {
        union { unsigned u[4]; bf16x8 v; } c0, c1;
#pragma unroll
        for (int m = 0; m < 4; ++m) {
            c0.u[m] = f2bf_pk(v16[2 * m], v16[2 * m + 1]);
            c1.u[m] = f2bf_pk(v16[8 + 2 * m], v16[9 + 2 * m]);
        }
        f0 = c0.v; f1 = c1.v;
    };

    float yv[8], yv2[8], xv[16];
    bf16x8 bf0, bf1;

    // ---- prologue: Y rows h0-4..h0+4 -> slots 0..8 (2-stage pipelined) ----
    loadY(h0 - KRAD, yv);
    loadX(h0, xv);
#pragma unroll 1
    for (int j = 0; j < 9; ++j) {
        if (j < 8) loadY(h0 - KRAD + j + 1, yv2);
        writeY(j, yv);
#pragma unroll
        for (int m = 0; m < 8; ++m) yv[m] = yv2[m];
    }
    xconv(xv, bf0, bf1);
    __syncthreads();

    // ---- main loop over h ----
#pragma unroll 1
    for (int hh = 0; hh < HT; ++hh) {
        const int h = h0 + hh;

        // issue next-iteration global loads early
        loadY(h + KRAD + 1, yv);
        loadX(h + 1, xv);

        float* outb = out + (size_t)b * ND * plane + (size_t)h * WW + (w0 + ln);

        // 18 (di,wt) units split across 4 waves: 5/5/4/4
        for (int u = wid; u < 18; u += 4) {
            const int di = u >> 1;
            const int wt = u & 1;
            const int slot = mod10(hh + di);
            const char* abase = ylds + slot * YSLOT + (wt * 16 + ln) * RSTRIDE;
            const unsigned sw = (unsigned)(ln & 7) << 4;
            bf16x8 af0 = *(const bf16x8*)(abase + (((unsigned)(lq * 16)) ^ sw));
            bf16x8 af1 = *(const bf16x8*)(abase + (((unsigned)(64 + lq * 16)) ^ sw));
            f32x4 dacc = {0.f, 0.f, 0.f, 0.f};
            dacc = __builtin_amdgcn_mfma_f32_16x16x32_bf16(af0, bf0, dacc, 0, 0, 0);
            dacc = __builtin_amdgcn_mfma_f32_16x16x32_bf16(af1, bf1, dacc, 0, 0, 0);
#pragma unroll
            for (int r = 0; r < 4; ++r) {
                int m  = lq * 4 + r;                 // w' row of D
                int dj = m - ln + (wt ? 12 : -KRAD); // displacement
                if ((unsigned)(dj + KRAD) <= 2u * KRAD) {
                    int didx = di * 9 + (dj + KRAD);
                    outb[(size_t)didx * plane] = dacc[r];
                }
            }
        }

        // stage next Y row (slot was retired; barrier-protected)
        writeY(mod10(hh + 9), yv);
        xconv(xv, bf0, bf1);

        // T4 counted-wait barrier: order LDS only; leave output stores and
        // prefetch loads in flight across the barrier (no vmcnt(0) drain).
        __builtin_amdgcn_sched_barrier(0);
        asm volatile("s_waitcnt lgkmcnt(0)" ::: "memory");
        __builtin_amdgcn_s_barrier();
        __builtin_amdgcn_sched_barrier(0);
    }
}

extern "C" void kernel_launch(void* const* d_in, const int* in_sizes, int n_in,
                              void* d_out, int out_size, void* d_ws, size_t ws_size,
                              hipStream_t stream) {
    const float* x = (const float*)d_in[0];
    const float* y = (const float*)d_in[1];
    float* out = (float*)d_out;

    dim3 grid(1024);   // 16 w-tiles * 16 h-tiles * 4 batch, XCD-swizzled in-kernel
    dim3 block(256);
    corr_mfma_kernel<<<grid, block, 0, stream>>>(x, y, out);
}

// Round 8
// 57.590 us; speedup vs baseline: 3.1036x; 1.4916x over previous
//
#include <hip/hip_runtime.h>

// corr via MFMA band extraction + LDS-transposed coalesced stores.
// out[b,(di)*9+(dj+4),h,w] = sum_c x[b,c,h,w] * y[b,c,refl(h+di-4),refl(w+dj)]
// A = Y_bf16[w'-tile, c], B = X_bf16[c, w-tile]; D[w',w] diagonals = dj.
// R8 = R4 + pstage: MFMA results ds_written to pstage[didx][w], then
// block-cooperative full-line global stores (16x fewer store transactions).

#define HH   256
#define WW   256
#define CCH  64
#define KRAD 4
#define ND   81

#define WT   16                 // output w per block
#define HT   16                 // output h per block
#define WY   24                 // staged y width = WT + 2*KRAD
#define RSTRIDE 128             // bytes per (row,w'): 64c*2B, XOR-swizzled chunks
#define YRING 10
#define YSLOT (WY * RSTRIDE)    // 3072 B
#define PSTRIDE 68              // pstage row stride (17 dwords: kills cross-lq conflicts)

typedef __attribute__((ext_vector_type(8))) short bf16x8;
typedef __attribute__((ext_vector_type(4))) float f32x4;

__device__ __forceinline__ int reflect(int v, int n) {
    v = v < 0 ? -v : v;
    return v >= n ? 2 * n - 2 - v : v;
}
__device__ __forceinline__ unsigned f2bf_pk(float a, float b) {
    union { float f; unsigned u; } xa, xb;
    xa.f = a; xb.f = b;
    unsigned ra = (xa.u + 0x7fffu + ((xa.u >> 16) & 1u)) >> 16;
    unsigned rb = (xb.u + 0x7fffu + ((xb.u >> 16) & 1u)) >> 16;
    return ra | (rb << 16);
}
__device__ __forceinline__ int mod10(int s) {   // s in [0, 30)
    if (s >= 20) s -= 20; else if (s >= 10) s -= 10;
    return s;
}

__global__ __launch_bounds__(256, 4) void corr_mfma_kernel(
    const float* __restrict__ x, const float* __restrict__ y,
    float* __restrict__ out)
{
    __shared__ char lds[YRING * YSLOT + ND * PSTRIDE + 12];  // 30720 + 5508 -> 36240 B, 4 blocks/CU
    char* ylds   = lds;
    char* pstage = lds + YRING * YSLOT;

    // XCD-chunked bijective swizzle: 1024 blocks = 8 XCDs * 128
    const int d  = blockIdx.x;
    const int v  = (d & 7) * 128 + (d >> 3);
    const int b  = v >> 8;
    const int by = (v >> 4) & 15;
    const int bx = v & 15;
    const int w0 = bx * WT;
    const int h0 = by * HT;

    const int t    = threadIdx.x;
    const int wid  = t >> 6;
    const int lane = t & 63;
    const int lq   = lane >> 4;      // 0..3
    const int ln   = lane & 15;      // 0..15

    const size_t plane = (size_t)HH * WW;
    const float* yb = y + (size_t)b * CCH * plane;
    const float* xb = x + (size_t)b * CCH * plane;

    // staging lane mapping for Y rows
    const int yp  = t & 31;          // w' position, active < WY
    const int ycg = t >> 5;          // c group: c = 8*ycg + j

    auto loadY = [&](int hrow, float* v8) {
        int gh = reflect(hrow, HH);
        int pc = yp < WY ? yp : WY - 1;
        int gw = reflect(w0 - KRAD + pc, WW);
        const float* src = yb + (size_t)(ycg * 8) * plane + (size_t)gh * WW + gw;
#pragma unroll
        for (int j = 0; j < 8; ++j) v8[j] = src[(size_t)j * plane];
    };
    auto writeY = [&](int slot, const float* v8) {
        if (yp < WY) {
            // XOR chunk-swizzle: 16B chunk index ^= (row & 7)
            char* dst = ylds + slot * YSLOT + yp * RSTRIDE
                      + (((unsigned)(ycg * 16)) ^ ((unsigned)(yp & 7) << 4));
            union { unsigned u[4]; uint4 q; } pk;
#pragma unroll
            for (int m = 0; m < 4; ++m)
                pk.u[m] = f2bf_pk(v8[2 * m], v8[2 * m + 1]);
            *(uint4*)dst = pk.q;
        }
    };
    // X direct-to-register: lane (lq,ln) holds B[c = lq*8+j (+32), w0+ln]
    auto loadX = [&](int hrow, float* v16) {
        int gh = reflect(hrow, HH);
        const float* src = xb + (size_t)(lq * 8) * plane + (size_t)gh * WW + (w0 + ln);
#pragma unroll
        for (int j = 0; j < 8; ++j) v16[j] = src[(size_t)j * plane];
        const float* src2 = src + (size_t)32 * plane;
#pragma unroll
        for (int j = 0; j < 8; ++j) v16[8 + j] = src2[(size_t)j * plane];
    };
    auto xconv = [&](const float* v16, bf16x8& f0, bf16x8& f1) {
        union { unsigned u[4]; bf16x8 v; } c0, c1;
#pragma unroll
        for (int m = 0; m < 4; ++m) {
            c0.u[m] = f2bf_pk(v16[2 * m], v16[2 * m + 1]);
            c1.u[m] = f2bf_pk(v16[8 + 2 * m], v16[9 + 2 * m]);
        }
        f0 = c0.v; f1 = c1.v;
    };

    float yv[8], yv2[8], xv[16];
    bf16x8 bf0, bf1;

    // ---- prologue: Y rows h0-4..h0+4 -> slots 0..8 (2-stage pipelined) ----
    loadY(h0 - KRAD, yv);
    loadX(h0, xv);
#pragma unroll 1
    for (int j = 0; j < 9; ++j) {
        if (j < 8) loadY(h0 - KRAD + j + 1, yv2);
        writeY(j, yv);
#pragma unroll
        for (int m = 0; m < 8; ++m) yv[m] = yv2[m];
    }
    xconv(xv, bf0, bf1);
    __syncthreads();

    const int mbase = lq * 4;        // D row m = mbase + r
    const int prow  = t >> 4;        // readback: didx sub-row
    const int pcol  = t & 15;        // readback: w column

    // ---- main loop over h ----
#pragma unroll 1
    for (int hh = 0; hh < HT; ++hh) {
        const int h = h0 + hh;

        // issue next-iteration global loads early
        loadY(h + KRAD + 1, yv);
        loadX(h + 1, xv);

        // 18 (di,wt) units split across 4 waves: 5/5/4/4
        for (int u = wid; u < 18; u += 4) {
            const int di = u >> 1;
            const int wt = u & 1;
            const int slot = mod10(hh + di);
            const char* abase = ylds + slot * YSLOT + (wt * 16 + ln) * RSTRIDE;
            const unsigned sw = (unsigned)(ln & 7) << 4;
            bf16x8 af0 = *(const bf16x8*)(abase + (((unsigned)(lq * 16)) ^ sw));
            bf16x8 af1 = *(const bf16x8*)(abase + (((unsigned)(64 + lq * 16)) ^ sw));
            f32x4 dacc = {0.f, 0.f, 0.f, 0.f};
            dacc = __builtin_amdgcn_mfma_f32_16x16x32_bf16(af0, bf0, dacc, 0, 0, 0);
            dacc = __builtin_amdgcn_mfma_f32_16x16x32_bf16(af1, bf1, dacc, 0, 0, 0);
            // transpose via LDS: pstage[didx][ln], didx = di*9 + (dj+4)
            char* psu = pstage + di * (9 * PSTRIDE) + ln * 4;
#pragma unroll
            for (int r = 0; r < 4; ++r) {
                const int vr = mbase + r - ln + (wt ? 16 : 0);   // dj+4
                if ((unsigned)vr <= 8u)
                    *(float*)(psu + vr * PSTRIDE) = dacc[r];
            }
        }

        // stage next Y row (slot retired; barrier-protected), next X -> regs
        writeY(mod10(hh + 9), yv);
        xconv(xv, bf0, bf1);

        // barrier 1: pstage + ring writes visible; stores/loads stay in flight
        __builtin_amdgcn_sched_barrier(0);
        asm volatile("s_waitcnt lgkmcnt(0)" ::: "memory");
        __builtin_amdgcn_s_barrier();
        __builtin_amdgcn_sched_barrier(0);

        // coalesced readback: 81 rows of 16 w (full 64B lines)
        {
            float* og = out + (size_t)b * ND * plane + (size_t)h * WW + (w0 + pcol);
#pragma unroll
            for (int p = 0; p < 6; ++p) {
                const int didx = p * 16 + prow;
                if (p < 5 || prow == 0) {
                    float vv = *(const float*)(pstage + didx * PSTRIDE + pcol * 4);
                    og[(size_t)didx * plane] = vv;
                }
            }
        }

        // barrier 2: readback done before next iter overwrites pstage
        __builtin_amdgcn_sched_barrier(0);
        __builtin_amdgcn_s_barrier();
        __builtin_amdgcn_sched_barrier(0);
    }
}

extern "C" void kernel_launch(void* const* d_in, const int* in_sizes, int n_in,
                              void* d_out, int out_size, void* d_ws, size_t ws_size,
                              hipStream_t stream) {
    const float* x = (const float*)d_in[0];
    const float* y = (const float*)d_in[1];
    float* out = (float*)d_out;

    dim3 grid(1024);   // 16 w-tiles * 16 h-tiles * 4 batch, XCD-swizzled in-kernel
    dim3 block(256);
    corr_mfma_kernel<<<grid, block, 0, stream>>>(x, y, out);
}